// Round 1
// baseline (482.403 us; speedup 1.0000x reference)
//
#include <hip/hip_runtime.h>
#include <math.h>

// Problem constants
#define B_  8
#define S_  512
#define D_  512
#define H_  8
#define DK_ 64
// rel table rows = 2*512-1 = 1023

// ---------------------------------------------------------------------------
// GEMM: C[M=4096, N=512] = A @ W^T + bias, K=512.
// A_MODE 0: A row-major [m, k]
// A_MODE 1: A stored as (b, h, s, dk): idx = ((b*8+h)*512+s)*64+dk, m=b*512+s, k=h*64+dk
// C_MODE 0: C row-major [m, n]
// C_MODE 1: C stored as (b, h, s, dk) with n = h*64+dk
// ---------------------------------------------------------------------------
template<int A_MODE, int C_MODE>
__global__ __launch_bounds__(256)
void gemm_wt_bias(const float* __restrict__ A, const float* __restrict__ W,
                  const float* __restrict__ bias, float* __restrict__ C) {
    // padded to 68 floats: rows stay 16B-aligned (272B) and banks spread
    __shared__ float As[16][68];
    __shared__ float Bs[16][68];
    const int tid = threadIdx.x;
    const int tx = tid & 15, ty = tid >> 4;
    const int m0 = blockIdx.y * 64, n0 = blockIdx.x * 64;
    float acc[4][4] = {};

    for (int k0 = 0; k0 < 512; k0 += 16) {
        const int kq = tid & 15;
        const int gk = k0 + kq;
        #pragma unroll
        for (int p = 0; p < 4; ++p) {
            const int mr = (tid >> 4) + p * 16;   // 0..63
            const int gm = m0 + mr;
            float av;
            if (A_MODE == 0) {
                av = A[(size_t)gm * 512 + gk];
            } else {
                const int b = gm >> 9, s = gm & 511, h = gk >> 6, dk = gk & 63;
                av = A[(((size_t)(b * 8 + h)) * 512 + s) * 64 + dk];
            }
            As[kq][mr] = av;
            Bs[kq][mr] = W[(size_t)(n0 + mr) * 512 + gk];   // Bs[k][n] = W[n][k]
        }
        __syncthreads();
        #pragma unroll
        for (int kk = 0; kk < 16; ++kk) {
            const float4 a4 = *(const float4*)&As[kk][ty * 4];
            const float4 b4 = *(const float4*)&Bs[kk][tx * 4];
            acc[0][0] += a4.x * b4.x; acc[0][1] += a4.x * b4.y; acc[0][2] += a4.x * b4.z; acc[0][3] += a4.x * b4.w;
            acc[1][0] += a4.y * b4.x; acc[1][1] += a4.y * b4.y; acc[1][2] += a4.y * b4.z; acc[1][3] += a4.y * b4.w;
            acc[2][0] += a4.z * b4.x; acc[2][1] += a4.z * b4.y; acc[2][2] += a4.z * b4.z; acc[2][3] += a4.z * b4.w;
            acc[3][0] += a4.w * b4.x; acc[3][1] += a4.w * b4.y; acc[3][2] += a4.w * b4.z; acc[3][3] += a4.w * b4.w;
        }
        __syncthreads();
    }

    const int gn0 = n0 + tx * 4;
    const float4 bi = *(const float4*)&bias[gn0];
    #pragma unroll
    for (int i = 0; i < 4; ++i) {
        const int gm = m0 + ty * 4 + i;
        float4 v;
        v.x = acc[i][0] + bi.x;
        v.y = acc[i][1] + bi.y;
        v.z = acc[i][2] + bi.z;
        v.w = acc[i][3] + bi.w;
        if (C_MODE == 0) {
            *(float4*)&C[(size_t)gm * 512 + gn0] = v;
        } else {
            const int b = gm >> 9, s = gm & 511, h = gn0 >> 6, dk = gn0 & 63;
            *(float4*)&C[(((size_t)(b * 8 + h)) * 512 + s) * 64 + dk] = v;
        }
    }
}

// ---------------------------------------------------------------------------
// Flash-style attention with relative position bias.
// Block: 256 threads handles one (b, h, 64-row q-tile). 4 threads per q row,
// each owning 16 k-columns (kk = quad + 4*kk2). Q row in registers.
// scores = (q.k)/8 + q.rel[k-q+511, h*64: h*64+64]   (rel term unscaled!)
// ---------------------------------------------------------------------------
__global__ __launch_bounds__(256, 2)
void attn_rel(const float* __restrict__ Q, const float* __restrict__ K,
              const float* __restrict__ V, const float* __restrict__ rel,
              float* __restrict__ O) {
    __shared__ float Ks[64][68];   // 17.4 KB
    __shared__ float Vs[64][68];   // 17.4 KB
    __shared__ float Rs[127][68];  // 34.5 KB  -> 69.3 KB total, 2 blocks/CU

    const int tid  = threadIdx.x;
    const int qq   = tid >> 2;    // 0..63: q row within tile
    const int quad = tid & 3;     // 4 threads per row
    const int q0   = blockIdx.x * 64;
    const int h    = blockIdx.y, b = blockIdx.z;
    const int bh   = b * H_ + h;

    // Q row -> registers (4 threads per row load redundantly; L1/L2 absorbs)
    const float* qptr = Q + ((size_t)bh * S_ + q0 + qq) * DK_;
    float4 q4r[16];
    #pragma unroll
    for (int i = 0; i < 16; ++i) q4r[i] = *(const float4*)(qptr + i * 4);

    float4 o4[16];
    #pragma unroll
    for (int i = 0; i < 16; ++i) o4[i] = make_float4(0.f, 0.f, 0.f, 0.f);
    float mrun = -INFINITY, lrun = 0.f;

    for (int kt = 0; kt < 8; ++kt) {
        const int k0 = kt * 64;
        const float* kbase = K + ((size_t)bh * S_ + k0) * DK_;
        const float* vbase = V + ((size_t)bh * S_ + k0) * DK_;
        for (int idx = tid; idx < 64 * 16; idx += 256) {
            const int r = idx >> 4, c = (idx & 15) * 4;
            *(float4*)&Ks[r][c] = *(const float4*)(kbase + r * 64 + c);
            *(float4*)&Vs[r][c] = *(const float4*)(vbase + r * 64 + c);
        }
        // rel rows j = (k0+kk) - (q0+qq) + 511, local index kk-qq+63 in [0,126]
        const int jbase = k0 - q0 + 448;   // always in [0, 896]
        const float* rbase = rel + (size_t)jbase * 512 + h * 64;
        for (int idx = tid; idx < 127 * 16; idx += 256) {
            const int r = idx >> 4, c = (idx & 15) * 4;
            *(float4*)&Rs[r][c] = *(const float4*)(rbase + (size_t)r * 512 + c);
        }
        __syncthreads();

        // scores for this tile
        float sc[16];
        #pragma unroll 4
        for (int kk2 = 0; kk2 < 16; ++kk2) {
            const int kk = quad + kk2 * 4;
            const float4* k4 = (const float4*)&Ks[kk][0];
            const float4* r4 = (const float4*)&Rs[kk - qq + 63][0];
            float s = 0.f, rr = 0.f;
            #pragma unroll
            for (int d4 = 0; d4 < 16; ++d4) {
                const float4 qv = q4r[d4];
                const float4 kv = k4[d4];
                const float4 rv = r4[d4];
                s  += qv.x * kv.x; s  += qv.y * kv.y; s  += qv.z * kv.z; s  += qv.w * kv.w;
                rr += qv.x * rv.x; rr += qv.y * rv.y; rr += qv.z * rv.z; rr += qv.w * rv.w;
            }
            sc[kk2] = s * 0.125f + rr;
        }

        // online softmax: row max across 4 threads
        float tmax = sc[0];
        #pragma unroll
        for (int i = 1; i < 16; ++i) tmax = fmaxf(tmax, sc[i]);
        tmax = fmaxf(tmax, __shfl_xor(tmax, 1));
        tmax = fmaxf(tmax, __shfl_xor(tmax, 2));
        const float mnew = fmaxf(mrun, tmax);
        const float corr = __expf(mrun - mnew);   // first tile: exp(-inf)=0
        lrun *= corr;
        #pragma unroll
        for (int d4 = 0; d4 < 16; ++d4) {
            o4[d4].x *= corr; o4[d4].y *= corr; o4[d4].z *= corr; o4[d4].w *= corr;
        }
        #pragma unroll 4
        for (int kk2 = 0; kk2 < 16; ++kk2) {
            const float p = __expf(sc[kk2] - mnew);
            lrun += p;
            const int kk = quad + kk2 * 4;
            const float4* v4 = (const float4*)&Vs[kk][0];
            #pragma unroll
            for (int d4 = 0; d4 < 16; ++d4) {
                const float4 vv = v4[d4];
                o4[d4].x += p * vv.x; o4[d4].y += p * vv.y;
                o4[d4].z += p * vv.z; o4[d4].w += p * vv.w;
            }
        }
        mrun = mnew;
        __syncthreads();
    }

    // reduce l and o across the 4 threads of each row
    lrun += __shfl_xor(lrun, 1);
    lrun += __shfl_xor(lrun, 2);
    const float invl = 1.0f / lrun;
    #pragma unroll
    for (int d4 = 0; d4 < 16; ++d4) {
        o4[d4].x += __shfl_xor(o4[d4].x, 1); o4[d4].x += __shfl_xor(o4[d4].x, 2);
        o4[d4].y += __shfl_xor(o4[d4].y, 1); o4[d4].y += __shfl_xor(o4[d4].y, 2);
        o4[d4].z += __shfl_xor(o4[d4].z, 1); o4[d4].z += __shfl_xor(o4[d4].z, 2);
        o4[d4].w += __shfl_xor(o4[d4].w, 1); o4[d4].w += __shfl_xor(o4[d4].w, 2);
    }
    // thread writes its 16-float slice: d in [quad*16, quad*16+16)
    float* optr = O + ((size_t)bh * S_ + q0 + qq) * DK_;
    #pragma unroll
    for (int d4 = 0; d4 < 4; ++d4) {
        const int di = quad * 4 + d4;
        float4 ov = o4[di];
        ov.x *= invl; ov.y *= invl; ov.z *= invl; ov.w *= invl;
        *(float4*)(optr + di * 4) = ov;
    }
}

// ---------------------------------------------------------------------------
extern "C" void kernel_launch(void* const* d_in, const int* in_sizes, int n_in,
                              void* d_out, int out_size, void* d_ws, size_t ws_size,
                              hipStream_t stream) {
    const float* x   = (const float*)d_in[0];
    const float* Wq  = (const float*)d_in[1];
    const float* bq  = (const float*)d_in[2];
    const float* Wk  = (const float*)d_in[3];
    const float* bk  = (const float*)d_in[4];
    const float* Wv  = (const float*)d_in[5];
    const float* bv  = (const float*)d_in[6];
    const float* Wo  = (const float*)d_in[7];
    const float* bo  = (const float*)d_in[8];
    const float* rel = (const float*)d_in[9];
    float* out = (float*)d_out;

    // workspace: Q | K | V, each B*H*S*DK = 2M floats (8 MB). 24 MB total.
    float* Qb = (float*)d_ws;
    float* Kb = Qb + (size_t)B_ * H_ * S_ * DK_;
    float* Vb = Kb + (size_t)B_ * H_ * S_ * DK_;

    dim3 gemm_grid(8, 64);   // (N/64, M/64)
    gemm_wt_bias<0, 1><<<gemm_grid, 256, 0, stream>>>(x, Wq, bq, Qb);
    gemm_wt_bias<0, 1><<<gemm_grid, 256, 0, stream>>>(x, Wk, bk, Kb);
    gemm_wt_bias<0, 1><<<gemm_grid, 256, 0, stream>>>(x, Wv, bv, Vb);

    // attention writes its output over Qb (each block writes exactly the rows
    // it read as Q, reads happen before writes with barriers in between)
    attn_rel<<<dim3(8, H_, B_), 256, 0, stream>>>(Qb, Kb, Vb, rel, Qb);

    // final projection reads head-interleaved layout, writes (B,S,512)
    gemm_wt_bias<1, 0><<<gemm_grid, 256, 0, stream>>>(Qb, Wo, bo, out);
}

// Round 2
// 223.161 us; speedup vs baseline: 2.1617x; 2.1617x over previous
//
#include <hip/hip_runtime.h>
#include <math.h>

// Problem constants
#define B_  8
#define S_  512
#define D_  512
#define H_  8
#define DK_ 64
// rel table rows = 2*512-1 = 1023; padded copy has 64 pad rows each side (1152 rows)

typedef __attribute__((ext_vector_type(8))) short short8;  // 8 bf16 = one MFMA A/B frag
typedef __attribute__((ext_vector_type(4))) float f32x4;   // MFMA C/D frag

#define MFMA_BF16(a, b, c) __builtin_amdgcn_mfma_f32_16x16x32_bf16(a, b, c, 0, 0, 0)

__device__ __forceinline__ unsigned bf16_rne(float x) {
    unsigned u = __float_as_uint(x);
    return (u + 0x7FFFu + ((u >> 16) & 1u)) >> 16;
}
__device__ __forceinline__ float bf16f(unsigned h) { return __uint_as_float(h << 16); }

// ---------------------------------------------------------------------------
// GEMM: C[M=4096, N=512] = A @ W^T + bias, K=512 (fp32 VALU, validated R1).
// A_MODE 0: A row-major [m,k];  A_MODE 1: A stored (b,h,s,dk)
// OUT_MODE 0: fp32 row-major [m,n] -> Cf
// OUT_MODE 2: split-bf16 planes (b,h,s,dk) -> Ch, Cl         (Q, K)
// OUT_MODE 3: split-bf16 planes TRANSPOSED (b,h,dk,s) -> Ch, Cl  (V)
// ---------------------------------------------------------------------------
template<int A_MODE, int OUT_MODE>
__global__ __launch_bounds__(256)
void gemm_wt_bias(const float* __restrict__ A, const float* __restrict__ W,
                  const float* __restrict__ bias, float* __restrict__ Cf,
                  ushort* __restrict__ Ch, ushort* __restrict__ Cl) {
    __shared__ float As[16][68];
    __shared__ float Bs[16][68];
    const int tid = threadIdx.x;
    const int tx = tid & 15, ty = tid >> 4;
    const int m0 = blockIdx.y * 64, n0 = blockIdx.x * 64;
    float acc[4][4] = {};

    for (int k0 = 0; k0 < 512; k0 += 16) {
        const int kq = tid & 15;
        const int gk = k0 + kq;
        #pragma unroll
        for (int p = 0; p < 4; ++p) {
            const int mr = (tid >> 4) + p * 16;
            const int gm = m0 + mr;
            float av;
            if (A_MODE == 0) {
                av = A[(size_t)gm * 512 + gk];
            } else {
                const int b = gm >> 9, s = gm & 511, h = gk >> 6, dk = gk & 63;
                av = A[(((size_t)(b * 8 + h)) * 512 + s) * 64 + dk];
            }
            As[kq][mr] = av;
            Bs[kq][mr] = W[(size_t)(n0 + mr) * 512 + gk];
        }
        __syncthreads();
        #pragma unroll
        for (int kk = 0; kk < 16; ++kk) {
            const float4 a4 = *(const float4*)&As[kk][ty * 4];
            const float4 b4 = *(const float4*)&Bs[kk][tx * 4];
            acc[0][0] += a4.x * b4.x; acc[0][1] += a4.x * b4.y; acc[0][2] += a4.x * b4.z; acc[0][3] += a4.x * b4.w;
            acc[1][0] += a4.y * b4.x; acc[1][1] += a4.y * b4.y; acc[1][2] += a4.y * b4.z; acc[1][3] += a4.y * b4.w;
            acc[2][0] += a4.z * b4.x; acc[2][1] += a4.z * b4.y; acc[2][2] += a4.z * b4.z; acc[2][3] += a4.z * b4.w;
            acc[3][0] += a4.w * b4.x; acc[3][1] += a4.w * b4.y; acc[3][2] += a4.w * b4.z; acc[3][3] += a4.w * b4.w;
        }
        __syncthreads();
    }

    const int gn0 = n0 + tx * 4;
    const float4 bi = *(const float4*)&bias[gn0];

    if (OUT_MODE == 0) {
        #pragma unroll
        for (int i = 0; i < 4; ++i) {
            const int gm = m0 + ty * 4 + i;
            float4 v;
            v.x = acc[i][0] + bi.x; v.y = acc[i][1] + bi.y;
            v.z = acc[i][2] + bi.z; v.w = acc[i][3] + bi.w;
            *(float4*)&Cf[(size_t)gm * 512 + gn0] = v;
        }
    } else if (OUT_MODE == 2) {
        #pragma unroll
        for (int i = 0; i < 4; ++i) {
            const int gm = m0 + ty * 4 + i;
            const int b = gm >> 9, s = gm & 511, hh = gn0 >> 6, dk0 = gn0 & 63;
            const size_t base = (((size_t)(b * 8 + hh)) * 512 + s) * 64 + dk0;
            float v[4] = {acc[i][0] + bi.x, acc[i][1] + bi.y, acc[i][2] + bi.z, acc[i][3] + bi.w};
            unsigned hb[4], lb[4];
            #pragma unroll
            for (int j = 0; j < 4; ++j) { hb[j] = bf16_rne(v[j]); lb[j] = bf16_rne(v[j] - bf16f(hb[j])); }
            *(uint2*)&Ch[base] = make_uint2(hb[0] | (hb[1] << 16), hb[2] | (hb[3] << 16));
            *(uint2*)&Cl[base] = make_uint2(lb[0] | (lb[1] << 16), lb[2] | (lb[3] << 16));
        }
    } else { // OUT_MODE == 3: V transposed (b,h,dk,s)
        const int gm0 = m0 + ty * 4;
        const int b = gm0 >> 9, s0 = gm0 & 511;
        const int hh = gn0 >> 6;
        #pragma unroll
        for (int j = 0; j < 4; ++j) {
            const int dk = (gn0 & 63) + j;
            const float bj = (&bi.x)[j];
            float v[4] = {acc[0][j] + bj, acc[1][j] + bj, acc[2][j] + bj, acc[3][j] + bj};
            unsigned hb[4], lb[4];
            #pragma unroll
            for (int q = 0; q < 4; ++q) { hb[q] = bf16_rne(v[q]); lb[q] = bf16_rne(v[q] - bf16f(hb[q])); }
            const size_t base = (((size_t)(b * 8 + hh)) * 64 + dk) * 512 + s0;
            *(uint2*)&Ch[base] = make_uint2(hb[0] | (hb[1] << 16), hb[2] | (hb[3] << 16));
            *(uint2*)&Cl[base] = make_uint2(lb[0] | (lb[1] << 16), lb[2] | (lb[3] << 16));
        }
    }
}

// ---------------------------------------------------------------------------
// rel_embed [1023][512] fp32 -> per-head padded bf16 table Rg[8][1152][64]
// (data at row offset +64; 64 zero pad rows each side so MFMA frag reads of
// out-of-range diagonal columns never fault)
// ---------------------------------------------------------------------------
__global__ __launch_bounds__(256)
void conv_rel(const float* __restrict__ rel, ushort* __restrict__ Rg) {
    const int idx = blockIdx.x * 256 + threadIdx.x;   // 8*1152*32 d-pairs
    const int d2 = idx & 31;
    const int rr = (idx >> 5) % 1152;
    const int h  = idx / (1152 * 32);
    unsigned v0 = 0, v1 = 0;
    if (rr >= 64 && rr < 64 + 1023) {
        const float* s = &rel[(size_t)(rr - 64) * 512 + h * 64 + d2 * 2];
        v0 = bf16_rne(s[0]); v1 = bf16_rne(s[1]);
    }
    *(uint*)&Rg[((size_t)h * 1152 + rr) * 64 + d2 * 2] = v0 | (v1 << 16);
}

// ---------------------------------------------------------------------------
// MFMA flash attention with relative position bias (split-bf16).
// Block = 256 threads = 4 waves; wave owns 32 q-rows (2 stripes of 16).
// grid = (4 q-chunks of 128, 64 bh).  K,V^T staged in LDS (XOR-swizzled);
// rel B-frags read from global (L2-resident); P via per-wave swizzled LDS.
// scores = (Q.K)/8 + Q.rel[k-q+511]; U[q][delta]=Q.R^T recovered diagonally
// with 2 shfl per element.
// ---------------------------------------------------------------------------
__global__ __launch_bounds__(256, 1)
void attn_mfma(const ushort* __restrict__ Qhp, const ushort* __restrict__ Qlp,
               const ushort* __restrict__ Khp, const ushort* __restrict__ Klp,
               const ushort* __restrict__ Vhp, const ushort* __restrict__ Vlp,
               const ushort* __restrict__ Rg, float* __restrict__ O) {
    __shared__ ushort Ksm[2][64 * 64];   // [plane][key][dk] 16B-chunk XOR-swizzled
    __shared__ ushort Vsm[2][64 * 64];   // [plane][dk][key] (V^T tile), swizzled
    __shared__ float  Psm[4][16 * 64];   // per-wave P buffer, chunk^row swizzled

    const int tid  = threadIdx.x;
    const int w    = tid >> 6;
    const int lane = tid & 63;
    const int g    = lane >> 4;
    const int c    = lane & 15;
    const int bh   = blockIdx.y;
    const int h    = bh & 7;
    const int qw   = blockIdx.x * 128 + w * 32;

    // hoist Q fragments: A-frag row = lane&15, d = g*8 + ks*32
    short8 qfh[2][2], qfl[2][2];
    #pragma unroll
    for (int st = 0; st < 2; ++st)
        #pragma unroll
        for (int ks = 0; ks < 2; ++ks) {
            const size_t qi = ((size_t)bh * 512 + qw + st * 16 + c) * 64 + ks * 32 + g * 8;
            qfh[st][ks] = *(const short8*)&Qhp[qi];
            qfl[st][ks] = *(const short8*)&Qlp[qi];
        }

    const f32x4 fz = {0.f, 0.f, 0.f, 0.f};
    f32x4 o[2][4];
    float mreg[2][4], lreg[2][4];
    #pragma unroll
    for (int st = 0; st < 2; ++st)
        #pragma unroll
        for (int i = 0; i < 4; ++i) { mreg[st][i] = -INFINITY; lreg[st][i] = 0.f; }
    #pragma unroll
    for (int st = 0; st < 2; ++st)
        #pragma unroll
        for (int dt = 0; dt < 4; ++dt) o[st][dt] = fz;

    const ushort* KhB = Khp + (size_t)bh * 512 * 64;
    const ushort* KlB = Klp + (size_t)bh * 512 * 64;
    const ushort* VhB = Vhp + (size_t)bh * 64 * 512;
    const ushort* VlB = Vlp + (size_t)bh * 64 * 512;

    for (int kt = 0; kt < 8; ++kt) {
        const int k0 = kt * 64;
        __syncthreads();   // previous tile's compute done before overwrite
        // ---- stage K/Klo/Vt/Vtlo tiles (reg-staged, source pre-swizzled) ----
        #pragma unroll
        for (int it = 0; it < 8; ++it) {
            const int plane = it >> 1;                 // compile-time after unroll
            const int cd  = ((it & 1) << 8) + tid;     // 0..511 16B-chunks
            const int row = cd >> 3, cc = cd & 7;
            const int sc  = cc ^ (row & 7);
            if (plane == 0) {
                uint4 v = *(const uint4*)&KhB[(size_t)(k0 + row) * 64 + sc * 8];
                *(uint4*)&Ksm[0][row * 64 + cc * 8] = v;
            } else if (plane == 1) {
                uint4 v = *(const uint4*)&KlB[(size_t)(k0 + row) * 64 + sc * 8];
                *(uint4*)&Ksm[1][row * 64 + cc * 8] = v;
            } else if (plane == 2) {
                uint4 v = *(const uint4*)&VhB[(size_t)row * 512 + k0 + sc * 8];
                *(uint4*)&Vsm[0][row * 64 + cc * 8] = v;
            } else {
                uint4 v = *(const uint4*)&VlB[(size_t)row * 512 + k0 + sc * 8];
                *(uint4*)&Vsm[1][row * 64 + cc * 8] = v;
            }
        }
        __syncthreads();

        #pragma unroll
        for (int st = 0; st < 2; ++st) {
            const int qs = qw + st * 16;

            // ---- U tiles: U[q][delta], 5 x 16 cols, from global rel ----
            f32x4 u[5];
            #pragma unroll
            for (int ut = 0; ut < 5; ++ut) u[ut] = fz;
            const int rrow0 = k0 - qs + 559 + c;   // rel row = delta + 511 + 64pad
            #pragma unroll
            for (int ks = 0; ks < 2; ++ks)
                #pragma unroll
                for (int ut = 0; ut < 5; ++ut) {
                    const short8 rf = *(const short8*)
                        &Rg[((size_t)h * 1152 + rrow0 + ut * 16) * 64 + ks * 32 + g * 8];
                    u[ut] = MFMA_BF16(qfh[st][ks], rf, u[ut]);
                }

            // ---- S tiles: Q.K^T, split-bf16 3-term ----
            f32x4 s[4];
            #pragma unroll
            for (int tc = 0; tc < 4; ++tc) s[tc] = fz;
            #pragma unroll
            for (int ks = 0; ks < 2; ++ks)
                #pragma unroll
                for (int tc = 0; tc < 4; ++tc) {
                    const int row = tc * 16 + c;
                    const int chv = ((ks * 4 + g) ^ (row & 7)) * 8;
                    const short8 kh8 = *(const short8*)&Ksm[0][row * 64 + chv];
                    const short8 kl8 = *(const short8*)&Ksm[1][row * 64 + chv];
                    s[tc] = MFMA_BF16(qfh[st][ks], kh8, s[tc]);
                    s[tc] = MFMA_BF16(qfl[st][ks], kh8, s[tc]);
                    s[tc] = MFMA_BF16(qfh[st][ks], kl8, s[tc]);
                }

            // ---- bias gather + online softmax + P write ----
            #pragma unroll
            for (int i = 0; i < 4; ++i) {
                const int r = g * 4 + i;                       // C/D row = (lane>>4)*4+reg
                const int srcl = (g << 4) | ((c - r) & 15);
                float sv[4];
                #pragma unroll
                for (int tc = 0; tc < 4; ++tc) {
                    const float va = __shfl(u[tc + 1][i], srcl);
                    const float vb = __shfl(u[tc][i], srcl);
                    sv[tc] = s[tc][i] * 0.125f + ((c >= r) ? va : vb);
                }
                float tm = fmaxf(fmaxf(sv[0], sv[1]), fmaxf(sv[2], sv[3]));
                tm = fmaxf(tm, __shfl_xor(tm, 1));
                tm = fmaxf(tm, __shfl_xor(tm, 2));
                tm = fmaxf(tm, __shfl_xor(tm, 4));
                tm = fmaxf(tm, __shfl_xor(tm, 8));
                const float mold = mreg[st][i];
                const float mn = fmaxf(mold, tm);
                const float corr = __expf(mold - mn);          // exp(-inf)=0 first tile
                mreg[st][i] = mn;
                float lacc = lreg[st][i] * corr;
                #pragma unroll
                for (int dt = 0; dt < 4; ++dt) o[st][dt][i] *= corr;
                #pragma unroll
                for (int tc = 0; tc < 4; ++tc) {
                    const float p = __expf(sv[tc] - mn);
                    lacc += p;
                    const int col = tc * 16 + c;
                    Psm[w][r * 64 + (((col >> 2) ^ r) << 2) + (col & 3)] = p;
                }
                lreg[st][i] = lacc;
            }
            asm volatile("s_waitcnt lgkmcnt(0)" ::: "memory");  // P writes visible to wave

            // ---- PV: O += P.V (split-bf16 3-term), V^T tile in LDS ----
            #pragma unroll
            for (int ks = 0; ks < 2; ++ks) {
                const int pc0 = ks * 8 + g * 2;
                const f32x4 pa = *(const f32x4*)&Psm[w][c * 64 + ((pc0 ^ c) << 2)];
                const f32x4 pb = *(const f32x4*)&Psm[w][c * 64 + (((pc0 + 1) ^ c) << 2)];
                short8 aph, apl;
                #pragma unroll
                for (int j = 0; j < 8; ++j) {
                    const float pj = (j < 4) ? pa[j] : pb[j - 4];
                    const unsigned hbits = bf16_rne(pj);
                    aph[j] = (short)hbits;
                    apl[j] = (short)bf16_rne(pj - bf16f(hbits));
                }
                #pragma unroll
                for (int dt = 0; dt < 4; ++dt) {
                    const int row = dt * 16 + c;
                    const int chv = ((ks * 4 + g) ^ (row & 7)) * 8;
                    const short8 vh8 = *(const short8*)&Vsm[0][row * 64 + chv];
                    const short8 vl8 = *(const short8*)&Vsm[1][row * 64 + chv];
                    o[st][dt] = MFMA_BF16(aph, vh8, o[st][dt]);
                    o[st][dt] = MFMA_BF16(aph, vl8, o[st][dt]);
                    o[st][dt] = MFMA_BF16(apl, vh8, o[st][dt]);
                }
            }
        } // stripe
    } // ktile

    // ---- finalize: reduce l across the 16-lane group, scale, store fp32 ----
    #pragma unroll
    for (int st = 0; st < 2; ++st) {
        const int qs = qw + st * 16;
        #pragma unroll
        for (int i = 0; i < 4; ++i) {
            float ls = lreg[st][i];
            ls += __shfl_xor(ls, 1);
            ls += __shfl_xor(ls, 2);
            ls += __shfl_xor(ls, 4);
            ls += __shfl_xor(ls, 8);
            const float inv = 1.0f / ls;
            const int r = g * 4 + i;
            #pragma unroll
            for (int dt = 0; dt < 4; ++dt)
                O[((size_t)bh * 512 + qs + r) * 64 + dt * 16 + c] = o[st][dt][i] * inv;
        }
    }
}

// ---------------------------------------------------------------------------
extern "C" void kernel_launch(void* const* d_in, const int* in_sizes, int n_in,
                              void* d_out, int out_size, void* d_ws, size_t ws_size,
                              hipStream_t stream) {
    const float* x   = (const float*)d_in[0];
    const float* Wq  = (const float*)d_in[1];
    const float* bq  = (const float*)d_in[2];
    const float* Wk  = (const float*)d_in[3];
    const float* bk  = (const float*)d_in[4];
    const float* Wv  = (const float*)d_in[5];
    const float* bv  = (const float*)d_in[6];
    const float* Wo  = (const float*)d_in[7];
    const float* bo  = (const float*)d_in[8];
    const float* rel = (const float*)d_in[9];
    float* out = (float*)d_out;

    // workspace: split-bf16 planes + padded rel + fp32 attn out  (~33 MB)
    const size_t NP = (size_t)B_ * H_ * S_ * DK_;   // 2,097,152
    ushort* Qh = (ushort*)d_ws;
    ushort* Ql = Qh + NP;
    ushort* Kh = Ql + NP;
    ushort* Kl = Kh + NP;
    ushort* Vh = Kl + NP;
    ushort* Vl = Vh + NP;
    ushort* Rg = Vl + NP;                 // 8*1152*64 = 589,824
    float*  Of = (float*)(Rg + 589824);   // 2M floats

    dim3 gemm_grid(8, 64);
    gemm_wt_bias<0, 2><<<gemm_grid, 256, 0, stream>>>(x, Wq, bq, nullptr, Qh, Ql);
    gemm_wt_bias<0, 2><<<gemm_grid, 256, 0, stream>>>(x, Wk, bk, nullptr, Kh, Kl);
    gemm_wt_bias<0, 3><<<gemm_grid, 256, 0, stream>>>(x, Wv, bv, nullptr, Vh, Vl);
    conv_rel<<<1152, 256, 0, stream>>>(rel, Rg);

    attn_mfma<<<dim3(4, 64), 256, 0, stream>>>(Qh, Ql, Kh, Kl, Vh, Vl, Rg, Of);

    gemm_wt_bias<1, 0><<<gemm_grid, 256, 0, stream>>>(Of, Wo, bo, out, nullptr, nullptr);
}

// Round 3
// 101.823 us; speedup vs baseline: 4.7377x; 2.1917x over previous
//
#include <hip/hip_runtime.h>
#include <math.h>

#define B_  8
#define S_  512
#define D_  512
#define H_  8
#define DK_ 64

typedef __attribute__((ext_vector_type(8))) short short8;
typedef __attribute__((ext_vector_type(4))) float f32x4;

#define MFMA_BF16(a, b, c) __builtin_amdgcn_mfma_f32_16x16x32_bf16(a, b, c, 0, 0, 0)

__device__ __forceinline__ unsigned bf16_rne(float x) {
    unsigned u = __float_as_uint(x);
    return (u + 0x7FFFu + ((u >> 16) & 1u)) >> 16;
}
__device__ __forceinline__ float bf16f(unsigned h) { return __uint_as_float(h << 16); }

// async global->LDS, 16B per lane; lds dest = uniform base + lane*16
__device__ __forceinline__ void glds16(const ushort* g, ushort* l) {
    __builtin_amdgcn_global_load_lds(
        (const __attribute__((address_space(1))) unsigned int*)g,
        (__attribute__((address_space(3))) unsigned int*)l,
        16, 0, 0);
}

// ---------------------------------------------------------------------------
// fp32 -> split-bf16 planes for x and the four weight matrices (one launch)
// x: 2M elems (blocks 0..2047); each W: 256K elems (256 blocks each)
// ---------------------------------------------------------------------------
__global__ __launch_bounds__(256)
void conv_pl(const float* __restrict__ x,
             const float* __restrict__ wq, const float* __restrict__ wk,
             const float* __restrict__ wv, const float* __restrict__ wo,
             ushort* __restrict__ Xh, ushort* __restrict__ Xl,
             ushort* __restrict__ Wqh, ushort* __restrict__ Wql,
             ushort* __restrict__ Wkh, ushort* __restrict__ Wkl,
             ushort* __restrict__ Wvh, ushort* __restrict__ Wvl,
             ushort* __restrict__ Woh, ushort* __restrict__ Wol) {
    const int bid = blockIdx.x;
    const float* src; ushort* dh; ushort* dl; int i4;
    if (bid < 2048) {
        src = x; dh = Xh; dl = Xl; i4 = bid * 256 + threadIdx.x;
    } else {
        const int r = bid - 2048;
        const int wsel = r >> 8;
        src = (wsel == 0) ? wq : (wsel == 1) ? wk : (wsel == 2) ? wv : wo;
        dh  = (wsel == 0) ? Wqh : (wsel == 1) ? Wkh : (wsel == 2) ? Wvh : Woh;
        dl  = (wsel == 0) ? Wql : (wsel == 1) ? Wkl : (wsel == 2) ? Wvl : Wol;
        i4 = (r & 255) * 256 + threadIdx.x;
    }
    const float4 v = ((const float4*)src)[i4];
    unsigned h[4], l[4];
    const float* vp = &v.x;
    #pragma unroll
    for (int j = 0; j < 4; ++j) { h[j] = bf16_rne(vp[j]); l[j] = bf16_rne(vp[j] - bf16f(h[j])); }
    ((uint2*)dh)[i4] = make_uint2(h[0] | (h[1] << 16), h[2] | (h[3] << 16));
    ((uint2*)dl)[i4] = make_uint2(l[0] | (l[1] << 16), l[2] | (l[3] << 16));
}

// ---------------------------------------------------------------------------
// rel_embed [1023][512] fp32 -> per-head padded bf16 table Rg[8][1152][64]
// ---------------------------------------------------------------------------
__global__ __launch_bounds__(256)
void conv_rel(const float* __restrict__ rel, ushort* __restrict__ Rg) {
    const int idx = blockIdx.x * 256 + threadIdx.x;
    const int d2 = idx & 31;
    const int rr = (idx >> 5) % 1152;
    const int h  = idx / (1152 * 32);
    unsigned v0 = 0, v1 = 0;
    if (rr >= 64 && rr < 64 + 1023) {
        const float* s = &rel[(size_t)(rr - 64) * 512 + h * 64 + d2 * 2];
        v0 = bf16_rne(s[0]); v1 = bf16_rne(s[1]);
    }
    *(uint*)&Rg[((size_t)h * 1152 + rr) * 64 + d2 * 2] = v0 | (v1 << 16);
}

// ---------------------------------------------------------------------------
// Split-bf16 MFMA GEMM: D[R][C] = X . Y^T (+bias), K=512, tile 64x64,
// 4 waves each 32x32, double-buffered LDS, glds staging (pre-swizzled src).
// XB: 0 = X row-major [r][512]; 1 = X planes in (b,h,s,dk) blocked layout
// OM: 0 = fp32 row-major out, bias[col]
//     2 = split planes (b,h,s,dk): row=(b,s), col=(h,dk), bias[col]   (Q,K)
//     3 = split planes (b,h,dk,s): row=(h,dk), col=(b,s), bias[row]   (V^T)
// grid.z selects {Y planes, bias, outputs} set 0/1 (used to fuse Q+K).
// ---------------------------------------------------------------------------
template<int XB, int OM>
__global__ __launch_bounds__(256, 2)
void gemm_mfma(const ushort* __restrict__ Xhp, const ushort* __restrict__ Xlp,
               const ushort* __restrict__ Yh0, const ushort* __restrict__ Yl0,
               const ushort* __restrict__ Yh1, const ushort* __restrict__ Yl1,
               const float* __restrict__ bias0, const float* __restrict__ bias1,
               float* __restrict__ outF,
               ushort* __restrict__ oh0, ushort* __restrict__ ol0,
               ushort* __restrict__ oh1, ushort* __restrict__ ol1) {
    __shared__ ushort Xs[2][2][64 * 64];   // [buf][plane][row*64+k]
    __shared__ ushort Ys[2][2][64 * 64];

    const int z = blockIdx.z;
    const ushort* Yhp = z ? Yh1 : Yh0;
    const ushort* Ylp = z ? Yl1 : Yl0;
    const float*  bias = z ? bias1 : bias0;
    ushort* ohp = z ? oh1 : oh0;
    ushort* olp = z ? ol1 : ol0;

    const int tid = threadIdx.x;
    const int w = tid >> 6, lane = tid & 63;
    const int g = lane >> 4, c = lane & 15;
    const int rloc = lane >> 3, cc8 = lane & 7;
    const int cp = cc8 ^ rloc;             // source chunk for linear-dest glds
    const int r0 = blockIdx.y * 64;        // X-row tile
    const int c0 = blockIdx.x * 64;        // Y-row (output col) tile

    const f32x4 fz = {0.f, 0.f, 0.f, 0.f};
    f32x4 acc[2][2] = {{fz, fz}, {fz, fz}};

    auto stage = [&](int kt, int buf) {
        const int k0 = kt * 64;
        const ushort* gb; ushort* lb; size_t rstr;
        if (w < 2) {
            const ushort* Xp = (w == 1) ? Xlp : Xhp;
            if (XB == 0) { gb = Xp + (size_t)r0 * 512 + k0; rstr = 512; }
            else {
                const int b = r0 >> 9, s0 = r0 & 511, h = k0 >> 6;
                gb = Xp + (((size_t)(b * 8 + h)) * 512 + s0) * 64; rstr = 64;
            }
            lb = &Xs[buf][w][0];
        } else {
            gb = ((w == 2) ? Yhp : Ylp) + (size_t)c0 * 512 + k0; rstr = 512;
            lb = &Ys[buf][w - 2][0];
        }
        #pragma unroll
        for (int j = 0; j < 8; ++j)
            glds16(gb + (size_t)(j * 8 + rloc) * rstr + cp * 8, lb + j * 512);
    };

    auto compute = [&](int buf) {
        #pragma unroll
        for (int ks = 0; ks < 2; ++ks) {
            short8 axh[2], axl[2], byh[2], byl[2];
            const int wm = (w >> 1) * 32, wn = (w & 1) * 32;
            #pragma unroll
            for (int t = 0; t < 2; ++t) {
                int row = wm + t * 16 + c;
                int off = row * 64 + (((ks * 4 + g) ^ (row & 7)) * 8);
                axh[t] = *(const short8*)&Xs[buf][0][off];
                axl[t] = *(const short8*)&Xs[buf][1][off];
                row = wn + t * 16 + c;
                off = row * 64 + (((ks * 4 + g) ^ (row & 7)) * 8);
                byh[t] = *(const short8*)&Ys[buf][0][off];
                byl[t] = *(const short8*)&Ys[buf][1][off];
            }
            #pragma unroll
            for (int tm = 0; tm < 2; ++tm)
                #pragma unroll
                for (int tn = 0; tn < 2; ++tn) {
                    acc[tm][tn] = MFMA_BF16(axh[tm], byh[tn], acc[tm][tn]);
                    acc[tm][tn] = MFMA_BF16(axl[tm], byh[tn], acc[tm][tn]);
                    acc[tm][tn] = MFMA_BF16(axh[tm], byl[tn], acc[tm][tn]);
                }
        }
    };

    stage(0, 0);
    __syncthreads();
    for (int kt = 0; kt < 8; ++kt) {
        if (kt < 7) stage(kt + 1, (kt + 1) & 1);   // prefetch overlaps compute
        compute(kt & 1);
        __syncthreads();                            // vmcnt(0) drain by compiler
    }

    const int wm = (w >> 1) * 32, wn = (w & 1) * 32;
    if (OM == 0) {
        #pragma unroll
        for (int tn = 0; tn < 2; ++tn) {
            const int gc = c0 + wn + tn * 16 + c;
            const float bv = bias[gc];
            #pragma unroll
            for (int tm = 0; tm < 2; ++tm)
                #pragma unroll
                for (int i = 0; i < 4; ++i) {
                    const int gr = r0 + wm + tm * 16 + g * 4 + i;
                    outF[(size_t)gr * 512 + gc] = acc[tm][tn][i] + bv;
                }
        }
    } else if (OM == 2) {
        #pragma unroll
        for (int tn = 0; tn < 2; ++tn) {
            const int gc = c0 + wn + tn * 16 + c;
            const int h = gc >> 6, dk = gc & 63;
            const float bv = bias[gc];
            #pragma unroll
            for (int tm = 0; tm < 2; ++tm)
                #pragma unroll
                for (int i = 0; i < 4; ++i) {
                    const int gr = r0 + wm + tm * 16 + g * 4 + i;
                    const int b = gr >> 9, s = gr & 511;
                    const float v = acc[tm][tn][i] + bv;
                    const unsigned hb = bf16_rne(v);
                    const size_t a = (((size_t)(b * 8 + h)) * 512 + s) * 64 + dk;
                    ohp[a] = (ushort)hb;
                    olp[a] = (ushort)bf16_rne(v - bf16f(hb));
                }
        }
    } else { // OM == 3: V^T
        #pragma unroll
        for (int tm = 0; tm < 2; ++tm)
            #pragma unroll
            for (int i = 0; i < 4; ++i) {
                const int gr = r0 + wm + tm * 16 + g * 4 + i;
                const int h = gr >> 6, dk = gr & 63;
                const float bv = bias[gr];
                #pragma unroll
                for (int tn = 0; tn < 2; ++tn) {
                    const int gc = c0 + wn + tn * 16 + c;
                    const int b = gc >> 9, s = gc & 511;
                    const float v = acc[tm][tn][i] + bv;
                    const unsigned hb = bf16_rne(v);
                    const size_t a = (((size_t)(b * 8 + h)) * 64 + dk) * 512 + s;
                    ohp[a] = (ushort)hb;
                    olp[a] = (ushort)bf16_rne(v - bf16f(hb));
                }
            }
    }
}

// ---------------------------------------------------------------------------
// MFMA flash attention with relative position bias (split-bf16).
// Block = 4 waves; wave owns 16 q-rows. grid = (8 q-chunks of 64, 64 bh).
// K/V^T staged via glds (pre-swizzled src); rel frags from global (L2);
// P via per-wave swizzled LDS. Output written as split-bf16 planes.
// ---------------------------------------------------------------------------
__global__ __launch_bounds__(256, 2)
void attn_mfma(const ushort* __restrict__ Qhp, const ushort* __restrict__ Qlp,
               const ushort* __restrict__ Khp, const ushort* __restrict__ Klp,
               const ushort* __restrict__ Vhp, const ushort* __restrict__ Vlp,
               const ushort* __restrict__ Rg,
               ushort* __restrict__ Oh, ushort* __restrict__ Ol) {
    __shared__ ushort Ksm[2][64 * 64];   // [plane][key][dk], chunk-swizzled
    __shared__ ushort Vsm[2][64 * 64];   // [plane][dk][key]
    __shared__ float  Psm[4][16 * 64];

    const int tid  = threadIdx.x;
    const int w    = tid >> 6;
    const int lane = tid & 63;
    const int g    = lane >> 4;
    const int c    = lane & 15;
    const int rloc = lane >> 3, cc8 = lane & 7;
    const int cp   = cc8 ^ rloc;
    const int bh   = blockIdx.y;
    const int h    = bh & 7;
    const int qw   = blockIdx.x * 64 + w * 16;

    short8 qfh[2], qfl[2];
    #pragma unroll
    for (int ks = 0; ks < 2; ++ks) {
        const size_t qi = ((size_t)bh * 512 + qw + c) * 64 + ks * 32 + g * 8;
        qfh[ks] = *(const short8*)&Qhp[qi];
        qfl[ks] = *(const short8*)&Qlp[qi];
    }

    const f32x4 fz = {0.f, 0.f, 0.f, 0.f};
    f32x4 o[4] = {fz, fz, fz, fz};
    float mreg[4], lreg[4];
    #pragma unroll
    for (int i = 0; i < 4; ++i) { mreg[i] = -INFINITY; lreg[i] = 0.f; }

    const ushort* KhB = Khp + (size_t)bh * 512 * 64;
    const ushort* KlB = Klp + (size_t)bh * 512 * 64;
    const ushort* VhB = Vhp + (size_t)bh * 64 * 512;
    const ushort* VlB = Vlp + (size_t)bh * 64 * 512;

    for (int kt = 0; kt < 8; ++kt) {
        const int k0 = kt * 64;
        __syncthreads();
        { // stage: wave w -> plane w (Kh, Kl, Vh^T, Vl^T)
            const ushort* gb; ushort* lb; size_t rstr;
            if (w == 0)      { gb = KhB + (size_t)k0 * 64; lb = &Ksm[0][0]; rstr = 64; }
            else if (w == 1) { gb = KlB + (size_t)k0 * 64; lb = &Ksm[1][0]; rstr = 64; }
            else if (w == 2) { gb = VhB + k0;              lb = &Vsm[0][0]; rstr = 512; }
            else             { gb = VlB + k0;              lb = &Vsm[1][0]; rstr = 512; }
            #pragma unroll
            for (int j = 0; j < 8; ++j)
                glds16(gb + (size_t)(j * 8 + rloc) * rstr + cp * 8, lb + j * 512);
        }
        __syncthreads();

        // ---- U tiles: U[q][delta] from global rel ----
        f32x4 u[5];
        #pragma unroll
        for (int ut = 0; ut < 5; ++ut) u[ut] = fz;
        const int rrow0 = k0 - qw + 559 + c;
        #pragma unroll
        for (int ks = 0; ks < 2; ++ks)
            #pragma unroll
            for (int ut = 0; ut < 5; ++ut) {
                const short8 rf = *(const short8*)
                    &Rg[((size_t)h * 1152 + rrow0 + ut * 16) * 64 + ks * 32 + g * 8];
                u[ut] = MFMA_BF16(qfh[ks], rf, u[ut]);
            }

        // ---- S = Q.K^T (3-term split) ----
        f32x4 s[4];
        #pragma unroll
        for (int tc = 0; tc < 4; ++tc) s[tc] = fz;
        #pragma unroll
        for (int ks = 0; ks < 2; ++ks)
            #pragma unroll
            for (int tc = 0; tc < 4; ++tc) {
                const int row = tc * 16 + c;
                const int chv = ((ks * 4 + g) ^ (row & 7)) * 8;
                const short8 kh8 = *(const short8*)&Ksm[0][row * 64 + chv];
                const short8 kl8 = *(const short8*)&Ksm[1][row * 64 + chv];
                s[tc] = MFMA_BF16(qfh[ks], kh8, s[tc]);
                s[tc] = MFMA_BF16(qfl[ks], kh8, s[tc]);
                s[tc] = MFMA_BF16(qfh[ks], kl8, s[tc]);
            }

        // ---- bias gather + online softmax + P write ----
        #pragma unroll
        for (int i = 0; i < 4; ++i) {
            const int r = g * 4 + i;
            const int srcl = (g << 4) | ((c - r) & 15);
            float sv[4];
            #pragma unroll
            for (int tc = 0; tc < 4; ++tc) {
                const float va = __shfl(u[tc + 1][i], srcl);
                const float vb = __shfl(u[tc][i], srcl);
                sv[tc] = s[tc][i] * 0.125f + ((c >= r) ? va : vb);
            }
            float tm = fmaxf(fmaxf(sv[0], sv[1]), fmaxf(sv[2], sv[3]));
            tm = fmaxf(tm, __shfl_xor(tm, 1));
            tm = fmaxf(tm, __shfl_xor(tm, 2));
            tm = fmaxf(tm, __shfl_xor(tm, 4));
            tm = fmaxf(tm, __shfl_xor(tm, 8));
            const float mold = mreg[i];
            const float mn = fmaxf(mold, tm);
            const float corr = __expf(mold - mn);
            mreg[i] = mn;
            float lacc = lreg[i] * corr;
            #pragma unroll
            for (int dt = 0; dt < 4; ++dt) o[dt][i] *= corr;
            #pragma unroll
            for (int tc = 0; tc < 4; ++tc) {
                const float p = __expf(sv[tc] - mn);
                lacc += p;
                const int col = tc * 16 + c;
                Psm[w][r * 64 + (((col >> 2) ^ r) << 2) + (col & 3)] = p;
            }
            lreg[i] = lacc;
        }
        asm volatile("s_waitcnt lgkmcnt(0)" ::: "memory");

        // ---- PV: O += P.V (3-term split) ----
        #pragma unroll
        for (int ks = 0; ks < 2; ++ks) {
            const int pc0 = ks * 8 + g * 2;
            const f32x4 pa = *(const f32x4*)&Psm[w][c * 64 + ((pc0 ^ c) << 2)];
            const f32x4 pb = *(const f32x4*)&Psm[w][c * 64 + (((pc0 + 1) ^ c) << 2)];
            short8 aph, apl;
            #pragma unroll
            for (int j = 0; j < 8; ++j) {
                const float pj = (j < 4) ? pa[j] : pb[j - 4];
                const unsigned hbits = bf16_rne(pj);
                aph[j] = (short)hbits;
                apl[j] = (short)bf16_rne(pj - bf16f(hbits));
            }
            #pragma unroll
            for (int dt = 0; dt < 4; ++dt) {
                const int row = dt * 16 + c;
                const int chv = ((ks * 4 + g) ^ (row & 7)) * 8;
                const short8 vh8 = *(const short8*)&Vsm[0][row * 64 + chv];
                const short8 vl8 = *(const short8*)&Vsm[1][row * 64 + chv];
                o[dt] = MFMA_BF16(aph, vh8, o[dt]);
                o[dt] = MFMA_BF16(aph, vl8, o[dt]);
                o[dt] = MFMA_BF16(apl, vh8, o[dt]);
            }
        }
    }

    // ---- finalize: reduce l, scale, store split-bf16 planes ----
    #pragma unroll
    for (int i = 0; i < 4; ++i) {
        float ls = lreg[i];
        ls += __shfl_xor(ls, 1);
        ls += __shfl_xor(ls, 2);
        ls += __shfl_xor(ls, 4);
        ls += __shfl_xor(ls, 8);
        const float inv = 1.0f / ls;
        const int r = g * 4 + i;
        #pragma unroll
        for (int dt = 0; dt < 4; ++dt) {
            const float val = o[dt][i] * inv;
            const unsigned hb = bf16_rne(val);
            const size_t a = ((size_t)bh * 512 + qw + r) * 64 + dt * 16 + c;
            Oh[a] = (ushort)hb;
            Ol[a] = (ushort)bf16_rne(val - bf16f(hb));
        }
    }
}

// ---------------------------------------------------------------------------
extern "C" void kernel_launch(void* const* d_in, const int* in_sizes, int n_in,
                              void* d_out, int out_size, void* d_ws, size_t ws_size,
                              hipStream_t stream) {
    const float* x   = (const float*)d_in[0];
    const float* Wq  = (const float*)d_in[1];
    const float* bq  = (const float*)d_in[2];
    const float* Wk  = (const float*)d_in[3];
    const float* bk  = (const float*)d_in[4];
    const float* Wv  = (const float*)d_in[5];
    const float* bv  = (const float*)d_in[6];
    const float* Wo  = (const float*)d_in[7];
    const float* bo  = (const float*)d_in[8];
    const float* rel = (const float*)d_in[9];
    float* out = (float*)d_out;

    const size_t NP = (size_t)B_ * H_ * S_ * DK_;   // 2,097,152
    const size_t WP = (size_t)D_ * D_;              //   262,144
    ushort* Xh  = (ushort*)d_ws;       // also reused as Oh after QKV gemms
    ushort* Xl  = Xh + NP;             // also Ol
    ushort* Wqh = Xl + NP;
    ushort* Wql = Wqh + WP;
    ushort* Wkh = Wql + WP;
    ushort* Wkl = Wkh + WP;
    ushort* Wvh = Wkl + WP;
    ushort* Wvl = Wvh + WP;
    ushort* Woh = Wvl + WP;
    ushort* Wol = Woh + WP;
    ushort* Qh  = Wol + WP;
    ushort* Ql  = Qh + NP;
    ushort* Kh  = Ql + NP;
    ushort* Kl  = Kh + NP;
    ushort* Vh  = Kl + NP;
    ushort* Vl  = Vh + NP;
    ushort* Rg  = Vl + NP;             // 8*1152*64 = 589,824

    conv_pl<<<3072, 256, 0, stream>>>(x, Wq, Wk, Wv, Wo,
                                      Xh, Xl, Wqh, Wql, Wkh, Wkl, Wvh, Wvl, Woh, Wol);
    conv_rel<<<1152, 256, 0, stream>>>(rel, Rg);

    // Q and K projections fused via grid.z
    gemm_mfma<0, 2><<<dim3(8, 64, 2), 256, 0, stream>>>(
        Xh, Xl, Wqh, Wql, Wkh, Wkl, bq, bk, nullptr, Qh, Ql, Kh, Kl);
    // V projection, operand-swapped -> V^T planes
    gemm_mfma<0, 3><<<dim3(64, 8, 1), 256, 0, stream>>>(
        Wvh, Wvl, Xh, Xl, nullptr, nullptr, bv, nullptr, nullptr, Vh, Vl, nullptr, nullptr);

    // attention: writes O planes over the X-plane region (x no longer needed)
    attn_mfma<<<dim3(8, 64), 256, 0, stream>>>(Qh, Ql, Kh, Kl, Vh, Vl, Rg, Xh, Xl);

    // output projection reads O planes (blocked layout), writes fp32
    gemm_mfma<1, 0><<<dim3(8, 64, 1), 256, 0, stream>>>(
        Xh, Xl, Woh, Wol, nullptr, nullptr, bo, nullptr, out, nullptr, nullptr, nullptr, nullptr);
}